// Round 5
// baseline (1992.643 us; speedup 1.0000x reference)
//
#include <hip/hip_runtime.h>
#include <hip/hip_fp16.h>
#include <hip/hip_cooperative_groups.h>

namespace cg = cooperative_groups;

#define DD 64
#define HC 384     // 2*D*L
#define SS 32
#define BINW 256   // nodes per bin (bin = dst >> 8); requires N < 65536
#define BSH 8
#define CAP 8192   // slab capacity per bin (avg load 4096 at E=800k)
#define CHUNK 2048 // edges per partition block

typedef _Float16 f16x8v __attribute__((ext_vector_type(8)));
typedef float f32x4v __attribute__((ext_vector_type(4)));

// ======================================================================
// MEGA-KERNEL: one cooperative dispatch replaces 9.
// Phases: A) edge-binning + prep  B) fine CSR  (G,N)x3 layers  F) final.
// grid.sync() + device-scope fences between phases (XCD L2 non-coherence).
// ======================================================================
__global__ __launch_bounds__(256, 6) void mega_kernel(
    const int* __restrict__ ei, const float* __restrict__ ew,
    int* __restrict__ bin_cur, unsigned* __restrict__ pk_slab,
    unsigned short* __restrict__ dl_slab,
    const float* __restrict__ x, __half* __restrict__ hh0,
    const float* __restrict__ W1, const float* __restrict__ W2,
    const float* __restrict__ gma, const float* __restrict__ bta,
    const float* __restrict__ bnm, const float* __restrict__ bnv,
    const float* __restrict__ b1, const float* __restrict__ b2,
    const float* __restrict__ epsv, const float* __restrict__ pmask,
    const int* __restrict__ batch, const int* __restrict__ mapping,
    const float* __restrict__ lw, const float* __restrict__ lb,
    __half* __restrict__ wpk, float* __restrict__ abbn,
    __half* __restrict__ zh, float* __restrict__ hcat,
    int* __restrict__ beg, int* __restrict__ endo,
    unsigned* __restrict__ packed, float* __restrict__ fout,
    int E, int N, int G, int nchunks, int nbins, int prepb)
{
  cg::grid_group gg = cg::this_grid();
  __shared__ union {
    struct { unsigned spk[CHUNK]; unsigned short sdst[CHUNK];
             int bcnt[256], boff[256], bcur[256], gbase[256], stmp[256]; } bp;
    struct { int cnt[256], loff[256], cur[256], stmp[256]; } fc;
    float tileF[DD * DD];                // 16 KB (union = 17.4 KB)
  } sh;
  const int t = threadIdx.x;
  const int wave = t >> 6;
  const int lane = t & 63;

#define GSYNC() { __threadfence(); gg.sync(); __threadfence(); }

  // ================= phase A: binning (vb < nchunks) + prep =================
  for (int vb = blockIdx.x; vb < nchunks + prepb; vb += gridDim.x) {
    if (vb < nchunks) {
      int e0 = vb * CHUNK;
      int m = min(CHUNK, E - e0);
      sh.bp.bcnt[t] = 0;
      __syncthreads();
      for (int i = t; i < m; i += 256)
        atomicAdd(&sh.bp.bcnt[ei[E + e0 + i] >> BSH], 1);
      __syncthreads();
      int v = sh.bp.bcnt[t];
      sh.bp.stmp[t] = v;
      __syncthreads();
      for (int o = 1; o < 256; o <<= 1) {
        int u = (t >= o) ? sh.bp.stmp[t - o] : 0;
        __syncthreads();
        sh.bp.stmp[t] += u;
        __syncthreads();
      }
      sh.bp.boff[t] = sh.bp.stmp[t] - v;
      sh.bp.bcur[t] = sh.bp.stmp[t] - v;
      if (v > 0) sh.bp.gbase[t] = atomicAdd(&bin_cur[t], v); // relative offsets
      __syncthreads();
      for (int i = t; i < m; i += 256) {
        unsigned d = (unsigned)ei[E + e0 + i];
        int b = d >> BSH;
        int p = atomicAdd(&sh.bp.bcur[b], 1);
        unsigned short wh = __half_as_ushort(__float2half(ew[e0 + i]));
        sh.bp.spk[p] = (unsigned)ei[e0 + i] | ((unsigned)wh << 16);
        sh.bp.sdst[p] = (unsigned short)d;
      }
      __syncthreads();
      for (int i = t; i < m; i += 256) {
        unsigned short d = sh.bp.sdst[i];
        int b = d >> BSH;
        int g = b * CAP + sh.bp.gbase[b] + (i - sh.bp.boff[b]);
        pk_slab[g] = sh.bp.spk[i];
        dl_slab[g] = d;
      }
      __syncthreads();
    } else {
      // ---------------- prep: W pack + BN fold + x->fp16 ----------------
      int gid = (vb - nchunks) * 256 + t;
      if (gid < 3072) {                  // 3 layers * 2 gemms * 8 frag-blks * 64
        int lane_ = gid & 63;
        int rest = gid >> 6;
        int kb = rest & 1;
        int nt = (rest >> 1) & 3;
        int gm = (rest >> 3) & 1;
        int ly = rest >> 4;
        const float* W = gm ? W2 : W1;
        int c = nt * 16 + (lane_ & 15);
        int k0 = kb * 32 + (lane_ >> 4) * 8;
        f16x8v o;
        #pragma unroll
        for (int j = 0; j < 8; ++j)
          o[j] = (_Float16)W[((size_t)ly * DD + k0 + j) * DD + c];
        *(f16x8v*)(wpk + gid * 8) = o;
      }
      if (gid >= 4096 && gid < 4288) {   // fold BN: A*t + B
        int id = gid - 4096;
        int ly = id >> 6, c = id & 63;
        float A = gma[ly * DD + c] * rsqrtf(bnv[ly * DD + c] + 1e-5f);
        float B = fmaf(b1[ly * DD + c] - bnm[ly * DD + c], A, bta[ly * DD + c]);
        abbn[ly * 128 + c] = A;
        abbn[ly * 128 + 64 + c] = B;
      }
      int i = gid * 8;
      if (i < N * DD) {
        float4 a = *(const float4*)(x + i);
        float4 b = *(const float4*)(x + i + 4);
        __half2 o[4];
        o[0] = __floats2half2_rn(a.x, a.y);
        o[1] = __floats2half2_rn(a.z, a.w);
        o[2] = __floats2half2_rn(b.x, b.y);
        o[3] = __floats2half2_rn(b.z, b.w);
        *(float4*)(hh0 + i) = *(float4*)o;
      }
    }
  }
  GSYNC();

  // ================= phase B: fine CSR (one block-iter per bin) =============
  for (int b = blockIdx.x; b < nbins; b += gridDim.x) {
    int sbase = b * CAP;
    int m = bin_cur[b];                  // relative count
    sh.fc.cnt[t] = 0;
    __syncthreads();
    for (int i = t; i < m; i += 256)
      atomicAdd(&sh.fc.cnt[dl_slab[sbase + i] & 255], 1);
    __syncthreads();
    int v = sh.fc.cnt[t];
    sh.fc.stmp[t] = v;
    __syncthreads();
    for (int o = 1; o < 256; o <<= 1) {
      int u = (t >= o) ? sh.fc.stmp[t - o] : 0;
      __syncthreads();
      sh.fc.stmp[t] += u;
      __syncthreads();
    }
    sh.fc.loff[t] = sh.fc.stmp[t] - v;
    sh.fc.cur[t] = sh.fc.loff[t];
    int node = b * BINW + t;
    if (node < N) {
      beg[node] = sbase + sh.fc.loff[t];
      endo[node] = sbase + sh.fc.loff[t] + v;
    }
    __syncthreads();
    for (int i = t; i < m; i += 256) {
      int dl = dl_slab[sbase + i] & 255;
      int p = atomicAdd(&sh.fc.cur[dl], 1);
      packed[sbase + p] = pk_slab[sbase + i];
    }
    __syncthreads();
  }
  GSYNC();

  // ================= 3 GIN layers =================
  const int sub = lane >> 3;             // gather: 0..7 edge-subgroup
  const int ch0 = (lane & 7) * 8;        // gather: 8 channels per lane
  const int g = lane >> 4;               // mfma: k-group
  const int cr = lane & 15;              // mfma: A-row / D-col within tile
  const int ntiles = (N + 63) >> 6;
  const int nwaves = gridDim.x * 4;

  for (int layer = 0; layer < 3; ++layer) {
    const __half* hh = hh0 + (size_t)layer * N * DD;
    __half* hhout = hh0 + (size_t)(layer + 1) * N * DD;
    const float e1 = 1.0f + epsv[layer];

    // ---- gather phase: 2 nodes per wave-task, grid-strided ----
    for (int task = blockIdx.x * 4 + wave; task * 2 < N; task += nwaves) {
      int na = task * 2;
      int nb = na + 1;
      bool hasB = nb < N;
      int ba = beg[na], ea_end = endo[na];
      int bb = hasB ? beg[nb] : 0, eb_end = hasB ? endo[nb] : 0;
      float accA[8] = {0, 0, 0, 0, 0, 0, 0, 0};
      float accB[8] = {0, 0, 0, 0, 0, 0, 0, 0};
      int ea = ba + sub, eb = bb + sub;
      while (ea < ea_end || eb < eb_end) {
        bool va = ea < ea_end;
        bool vb = eb < eb_end;
        unsigned pa = 0, pb = 0;
        if (va) pa = packed[ea];
        if (vb) pb = packed[eb];
        float4 ra, rb;
        if (va) ra = *(const float4*)(hh + (size_t)(pa & 0xffffu) * DD + ch0);
        if (vb) rb = *(const float4*)(hh + (size_t)(pb & 0xffffu) * DD + ch0);
        if (va) {
          float w = __half2float(__ushort_as_half((unsigned short)(pa >> 16)));
          const __half2* H = (const __half2*)&ra;
          #pragma unroll
          for (int j = 0; j < 4; ++j) {
            float2 f = __half22float2(H[j]);
            accA[2 * j]     = fmaf(w, f.x, accA[2 * j]);
            accA[2 * j + 1] = fmaf(w, f.y, accA[2 * j + 1]);
          }
        }
        if (vb) {
          float w = __half2float(__ushort_as_half((unsigned short)(pb >> 16)));
          const __half2* H = (const __half2*)&rb;
          #pragma unroll
          for (int j = 0; j < 4; ++j) {
            float2 f = __half22float2(H[j]);
            accB[2 * j]     = fmaf(w, f.x, accB[2 * j]);
            accB[2 * j + 1] = fmaf(w, f.y, accB[2 * j + 1]);
          }
        }
        ea += 8; eb += 8;
      }
      #pragma unroll
      for (int j = 0; j < 8; ++j) {
        accA[j] += __shfl_xor(accA[j], 8);
        accA[j] += __shfl_xor(accA[j], 16);
        accA[j] += __shfl_xor(accA[j], 32);
        accB[j] += __shfl_xor(accB[j], 8);
        accB[j] += __shfl_xor(accB[j], 16);
        accB[j] += __shfl_xor(accB[j], 32);
      }
      if (sub == 0) {
        {
          float4 sr = *(const float4*)(hh + (size_t)na * DD + ch0);
          const __half2* S = (const __half2*)&sr;
          f16x8v q;
          #pragma unroll
          for (int j = 0; j < 4; ++j) {
            float2 f = __half22float2(S[j]);
            q[2 * j]     = (_Float16)fmaf(e1, f.x, accA[2 * j]);
            q[2 * j + 1] = (_Float16)fmaf(e1, f.y, accA[2 * j + 1]);
          }
          *(f16x8v*)(zh + (size_t)na * DD + ch0) = q;
        }
        if (hasB) {
          float4 sr = *(const float4*)(hh + (size_t)nb * DD + ch0);
          const __half2* S = (const __half2*)&sr;
          f16x8v q;
          #pragma unroll
          for (int j = 0; j < 4; ++j) {
            float2 f = __half22float2(S[j]);
            q[2 * j]     = (_Float16)fmaf(e1, f.x, accB[2 * j]);
            q[2 * j + 1] = (_Float16)fmaf(e1, f.y, accB[2 * j + 1]);
          }
          *(f16x8v*)(zh + (size_t)nb * DD + ch0) = q;
        }
      }
    }
    GSYNC();

    // ---- node MFMA phase: 64-node tiles, grid-strided ----
    const __half* wl  = wpk + (size_t)layer * 8192;
    const __half* w2l = wl + 4096;
    __half* tileH = (__half*)sh.tileF;
    for (int tile = blockIdx.x; tile < ntiles; tile += gridDim.x) {
      const int n0 = tile * 64;
      const int mrow = n0 + wave * 16 + cr;
      // GEMM1: z @ W1
      f16x8v a0 = *(const f16x8v*)(zh + (size_t)mrow * DD + g * 8);
      f16x8v a1 = *(const f16x8v*)(zh + (size_t)mrow * DD + 32 + g * 8);
      f32x4v acc1[4];
      #pragma unroll
      for (int nt = 0; nt < 4; ++nt) {
        f16x8v b0 = *(const f16x8v*)(wl + (nt * 2 + 0) * 512 + lane * 8);
        f16x8v b1f = *(const f16x8v*)(wl + (nt * 2 + 1) * 512 + lane * 8);
        acc1[nt] = (f32x4v){0.f, 0.f, 0.f, 0.f};
        acc1[nt] = __builtin_amdgcn_mfma_f32_16x16x32_f16(a0, b0, acc1[nt], 0, 0, 0);
        acc1[nt] = __builtin_amdgcn_mfma_f32_16x16x32_f16(a1, b1f, acc1[nt], 0, 0, 0);
      }
      // epilogue1: BN + ReLU -> fp16 LDS (XOR-swizzled)
      #pragma unroll
      for (int nt = 0; nt < 4; ++nt) {
        int c = nt * 16 + cr;
        float Ab = abbn[layer * 128 + c];
        float Bb = abbn[layer * 128 + 64 + c];
        #pragma unroll
        for (int r = 0; r < 4; ++r) {
          int row = wave * 16 + g * 4 + r;
          float v = fmaxf(fmaf(acc1[nt][r], Ab, Bb), 0.f);
          tileH[row * DD + (((c >> 3) ^ (row & 7)) * 8) + (c & 7)] = __float2half(v);
        }
      }
      __syncthreads();
      // GEMM2: act @ W2
      const int arow = wave * 16 + cr;
      f16x8v a20 = *(const f16x8v*)(tileH + arow * DD + ((g ^ (arow & 7)) * 8));
      f16x8v a21 = *(const f16x8v*)(tileH + arow * DD + (((4 + g) ^ (arow & 7)) * 8));
      f32x4v acc2[4];
      #pragma unroll
      for (int nt = 0; nt < 4; ++nt) {
        f16x8v b0 = *(const f16x8v*)(w2l + (nt * 2 + 0) * 512 + lane * 8);
        f16x8v b1f = *(const f16x8v*)(w2l + (nt * 2 + 1) * 512 + lane * 8);
        acc2[nt] = (f32x4v){0.f, 0.f, 0.f, 0.f};
        acc2[nt] = __builtin_amdgcn_mfma_f32_16x16x32_f16(a20, b0, acc2[nt], 0, 0, 0);
        acc2[nt] = __builtin_amdgcn_mfma_f32_16x16x32_f16(a21, b1f, acc2[nt], 0, 0, 0);
      }
      __syncthreads();
      // epilogue2: +b2, ReLU -> fp32 LDS (rotate-skewed)
      #pragma unroll
      for (int nt = 0; nt < 4; ++nt) {
        int c = nt * 16 + cr;
        float bb = b2[layer * DD + c];
        #pragma unroll
        for (int r = 0; r < 4; ++r) {
          int row = wave * 16 + g * 4 + r;
          sh.tileF[row * DD + ((c + row) & 63)] = fmaxf(acc2[nt][r] + bb, 0.f);
        }
      }
      __syncthreads();
      // copy-out h fp16, coalesced
      #pragma unroll
      for (int i = 0; i < 2; ++i) {
        int id = i * 256 + t;
        int rw = id >> 3, q = id & 7;
        if (n0 + rw < N) {
          f16x8v hv;
          #pragma unroll
          for (int j = 0; j < 8; ++j)
            hv[j] = (_Float16)sh.tileF[rw * DD + ((q * 8 + j + rw) & 63)];
          *(f16x8v*)(hhout + (size_t)(n0 + rw) * DD + q * 8) = hv;
        }
      }
      // pooling (fp32-exact)
      float accp = 0.0f;
      int gcur = -1;
      for (int i = 0; i < 16; ++i) {
        int r = wave * 16 + i;
        int n = n0 + r;
        if (n >= N) break;
        float v = sh.tileF[r * DD + ((lane + r) & 63)];
        int gb = batch[n];
        if (gb != gcur) {
          if (gcur >= 0) atomicAdd(&hcat[gcur * HC + layer * 128 + lane], accp);
          gcur = gb; accp = 0.0f;
        }
        accp = fmaf(v, pmask[n], accp);
      }
      if (gcur >= 0) atomicAdd(&hcat[gcur * HC + layer * 128 + lane], accp);
      __syncthreads();   // protect tileF/tileH reuse on next tile iteration
    }
    GSYNC();
  }

  // ================= phase F: final linear =================
  const __half* h1 = hh0 + (size_t)1 * N * DD;
  const __half* h2 = hh0 + (size_t)2 * N * DD;
  const __half* h3 = hh0 + (size_t)3 * N * DD;
  for (int gid = blockIdx.x * 256 + t; gid < G * SS; gid += gridDim.x * 256) {
    int gi = gid >> 5, s = gid & 31;
    float acc = lb[s];
    size_t mr = (size_t)mapping[gi] * DD;
    #pragma unroll
    for (int l = 0; l < 3; ++l) {
      const float* hc = hcat + gi * HC + l * 128;
      const float* lwa = lw + (l * 128) * SS + s;
      #pragma unroll 4
      for (int c = 0; c < 64; ++c)
        acc = fmaf(hc[c], lwa[c * SS], acc);
      const __half* hr = ((l == 0) ? h1 : ((l == 1) ? h2 : h3)) + mr;
      const float* lwc = lw + (l * 128 + 64) * SS + s;
      #pragma unroll 4
      for (int c = 0; c < 64; ++c)
        acc = fmaf(__half2float(hr[c]), lwc[c * SS], acc);
    }
    fout[gi * SS + s] = acc;
  }
#undef GSYNC
}

// ======================================================================
// Fallback path (classic split dispatches) — used only if the cooperative
// launch is rejected by the runtime.
// ======================================================================
__global__ __launch_bounds__(256) void front_kernel(
    const int* __restrict__ ei, const float* __restrict__ ew,
    int* __restrict__ bin_cur, unsigned* __restrict__ pk_slab,
    unsigned short* __restrict__ dl_slab, int E, int nchunks,
    const float* __restrict__ x, __half* __restrict__ hh0,
    const float* __restrict__ W1, const float* __restrict__ W2,
    const float* __restrict__ gma, const float* __restrict__ bta,
    const float* __restrict__ bnm, const float* __restrict__ bnv,
    const float* __restrict__ b1, __half* __restrict__ wpk,
    float* __restrict__ abbn, int total)
{
  __shared__ unsigned spk[CHUNK];
  __shared__ unsigned short sdst[CHUNK];
  __shared__ int bcnt[256], boff[256], bcur[256], gbase[256], stmp[256];
  int t = threadIdx.x;
  if ((int)blockIdx.x >= nchunks) {
    int gid = (blockIdx.x - nchunks) * 256 + t;
    if (gid < 3072) {
      int lane_ = gid & 63;
      int rest = gid >> 6;
      int kb = rest & 1;
      int nt = (rest >> 1) & 3;
      int gm = (rest >> 3) & 1;
      int ly = rest >> 4;
      const float* W = gm ? W2 : W1;
      int c = nt * 16 + (lane_ & 15);
      int k0 = kb * 32 + (lane_ >> 4) * 8;
      f16x8v o;
      #pragma unroll
      for (int j = 0; j < 8; ++j)
        o[j] = (_Float16)W[((size_t)ly * DD + k0 + j) * DD + c];
      *(f16x8v*)(wpk + gid * 8) = o;
    }
    if (gid >= 4096 && gid < 4288) {
      int id = gid - 4096;
      int ly = id >> 6, c = id & 63;
      float A = gma[ly * DD + c] * rsqrtf(bnv[ly * DD + c] + 1e-5f);
      float B = fmaf(b1[ly * DD + c] - bnm[ly * DD + c], A, bta[ly * DD + c]);
      abbn[ly * 128 + c] = A;
      abbn[ly * 128 + 64 + c] = B;
    }
    int i = gid * 8;
    if (i < total) {
      float4 a = *(const float4*)(x + i);
      float4 b = *(const float4*)(x + i + 4);
      __half2 o[4];
      o[0] = __floats2half2_rn(a.x, a.y);
      o[1] = __floats2half2_rn(a.z, a.w);
      o[2] = __floats2half2_rn(b.x, b.y);
      o[3] = __floats2half2_rn(b.z, b.w);
      *(float4*)(hh0 + i) = *(float4*)o;
    }
    return;
  }
  int e0 = blockIdx.x * CHUNK;
  int m = min(CHUNK, E - e0);
  bcnt[t] = 0;
  __syncthreads();
  for (int i = t; i < m; i += 256)
    atomicAdd(&bcnt[ei[E + e0 + i] >> BSH], 1);
  __syncthreads();
  int v = bcnt[t];
  stmp[t] = v;
  __syncthreads();
  for (int o = 1; o < 256; o <<= 1) {
    int u = (t >= o) ? stmp[t - o] : 0;
    __syncthreads();
    stmp[t] += u;
    __syncthreads();
  }
  boff[t] = stmp[t] - v;
  bcur[t] = stmp[t] - v;
  if (v > 0) gbase[t] = atomicAdd(&bin_cur[t], v);
  __syncthreads();
  for (int i = t; i < m; i += 256) {
    unsigned d = (unsigned)ei[E + e0 + i];
    int b = d >> BSH;
    int p = atomicAdd(&bcur[b], 1);
    unsigned short wh = __half_as_ushort(__float2half(ew[e0 + i]));
    spk[p] = (unsigned)ei[e0 + i] | ((unsigned)wh << 16);
    sdst[p] = (unsigned short)d;
  }
  __syncthreads();
  for (int i = t; i < m; i += 256) {
    unsigned short d = sdst[i];
    int b = d >> BSH;
    int g = b * CAP + gbase[b] + (i - boff[b]);
    pk_slab[g] = spk[i];
    dl_slab[g] = d;
  }
}

__global__ __launch_bounds__(256) void fine_csr_kernel(
    const unsigned* __restrict__ pk_slab,
    const unsigned short* __restrict__ dl_slab,
    const int* __restrict__ bin_cur, int* __restrict__ beg,
    int* __restrict__ endo, unsigned* __restrict__ packed, int N)
{
  __shared__ int cnt[256], loff[256], cur[256], stmp[256];
  int t = threadIdx.x;
  int b = blockIdx.x;
  int sbase = b * CAP;
  int m = bin_cur[b];
  cnt[t] = 0;
  __syncthreads();
  for (int i = t; i < m; i += 256)
    atomicAdd(&cnt[dl_slab[sbase + i] & 255], 1);
  __syncthreads();
  int v = cnt[t];
  stmp[t] = v;
  __syncthreads();
  for (int o = 1; o < 256; o <<= 1) {
    int u = (t >= o) ? stmp[t - o] : 0;
    __syncthreads();
    stmp[t] += u;
    __syncthreads();
  }
  loff[t] = stmp[t] - v;
  cur[t] = loff[t];
  int node = b * BINW + t;
  if (node < N) {
    beg[node] = sbase + loff[t];
    endo[node] = sbase + loff[t] + v;
  }
  __syncthreads();
  for (int i = t; i < m; i += 256) {
    int dl = dl_slab[sbase + i] & 255;
    int p = atomicAdd(&cur[dl], 1);
    packed[sbase + p] = pk_slab[sbase + i];
  }
}

__global__ __launch_bounds__(256) void gather_kernel(
    const __half* __restrict__ hh, const unsigned* __restrict__ packed,
    const int* __restrict__ begA, const int* __restrict__ endA,
    const float* __restrict__ epsv, __half* __restrict__ zh, int layer, int N)
{
  int wave = threadIdx.x >> 6;
  int lane = threadIdx.x & 63;
  int sub = lane >> 3;
  int ch0 = (lane & 7) * 8;
  int na = blockIdx.x * 8 + wave * 2;
  int nb = na + 1;
  if (na >= N) return;
  bool hasB = nb < N;
  int bega = begA[na], enda = endA[na];
  int begb = hasB ? begA[nb] : 0, endb = hasB ? endA[nb] : 0;
  float accA[8] = {0, 0, 0, 0, 0, 0, 0, 0};
  float accB[8] = {0, 0, 0, 0, 0, 0, 0, 0};
  int ea = bega + sub, eb = begb + sub;
  while (ea < enda || eb < endb) {
    bool va = ea < enda;
    bool vb = eb < endb;
    unsigned pa = 0, pb = 0;
    if (va) pa = packed[ea];
    if (vb) pb = packed[eb];
    float4 ra, rb;
    if (va) ra = *(const float4*)(hh + (size_t)(pa & 0xffffu) * DD + ch0);
    if (vb) rb = *(const float4*)(hh + (size_t)(pb & 0xffffu) * DD + ch0);
    if (va) {
      float w = __half2float(__ushort_as_half((unsigned short)(pa >> 16)));
      const __half2* H = (const __half2*)&ra;
      #pragma unroll
      for (int j = 0; j < 4; ++j) {
        float2 f = __half22float2(H[j]);
        accA[2 * j]     = fmaf(w, f.x, accA[2 * j]);
        accA[2 * j + 1] = fmaf(w, f.y, accA[2 * j + 1]);
      }
    }
    if (vb) {
      float w = __half2float(__ushort_as_half((unsigned short)(pb >> 16)));
      const __half2* H = (const __half2*)&rb;
      #pragma unroll
      for (int j = 0; j < 4; ++j) {
        float2 f = __half22float2(H[j]);
        accB[2 * j]     = fmaf(w, f.x, accB[2 * j]);
        accB[2 * j + 1] = fmaf(w, f.y, accB[2 * j + 1]);
      }
    }
    ea += 8; eb += 8;
  }
  #pragma unroll
  for (int j = 0; j < 8; ++j) {
    accA[j] += __shfl_xor(accA[j], 8);
    accA[j] += __shfl_xor(accA[j], 16);
    accA[j] += __shfl_xor(accA[j], 32);
    accB[j] += __shfl_xor(accB[j], 8);
    accB[j] += __shfl_xor(accB[j], 16);
    accB[j] += __shfl_xor(accB[j], 32);
  }
  if (sub == 0) {
    float e1 = 1.0f + epsv[layer];
    {
      float4 sr = *(const float4*)(hh + (size_t)na * DD + ch0);
      const __half2* S = (const __half2*)&sr;
      f16x8v q;
      #pragma unroll
      for (int j = 0; j < 4; ++j) {
        float2 f = __half22float2(S[j]);
        q[2 * j]     = (_Float16)fmaf(e1, f.x, accA[2 * j]);
        q[2 * j + 1] = (_Float16)fmaf(e1, f.y, accA[2 * j + 1]);
      }
      *(f16x8v*)(zh + (size_t)na * DD + ch0) = q;
    }
    if (hasB) {
      float4 sr = *(const float4*)(hh + (size_t)nb * DD + ch0);
      const __half2* S = (const __half2*)&sr;
      f16x8v q;
      #pragma unroll
      for (int j = 0; j < 4; ++j) {
        float2 f = __half22float2(S[j]);
        q[2 * j]     = (_Float16)fmaf(e1, f.x, accB[2 * j]);
        q[2 * j + 1] = (_Float16)fmaf(e1, f.y, accB[2 * j + 1]);
      }
      *(f16x8v*)(zh + (size_t)nb * DD + ch0) = q;
    }
  }
}

__global__ __launch_bounds__(256) void node_mfma_kernel(
    const __half* __restrict__ zh, __half* __restrict__ hhout,
    const __half* __restrict__ wpk, const float* __restrict__ abbn,
    const float* __restrict__ b2, const float* __restrict__ pmask,
    const int* __restrict__ batch, float* __restrict__ hcat,
    int layer, int N)
{
  __shared__ float tileF[DD * DD];
  __half* tileH = (__half*)tileF;
  const int wave = threadIdx.x >> 6;
  const int lane = threadIdx.x & 63;
  const int g = lane >> 4;
  const int cr = lane & 15;
  const int n0 = blockIdx.x * 64;
  const int mrow = n0 + wave * 16 + cr;
  const __half* wl  = wpk + (size_t)layer * 8192;
  const __half* w2l = wl + 4096;
  f16x8v a0 = *(const f16x8v*)(zh + (size_t)mrow * DD + g * 8);
  f16x8v a1 = *(const f16x8v*)(zh + (size_t)mrow * DD + 32 + g * 8);
  f32x4v acc[4];
  #pragma unroll
  for (int nt = 0; nt < 4; ++nt) {
    f16x8v b0 = *(const f16x8v*)(wl + (nt * 2 + 0) * 512 + lane * 8);
    f16x8v b1 = *(const f16x8v*)(wl + (nt * 2 + 1) * 512 + lane * 8);
    acc[nt] = (f32x4v){0.f, 0.f, 0.f, 0.f};
    acc[nt] = __builtin_amdgcn_mfma_f32_16x16x32_f16(a0, b0, acc[nt], 0, 0, 0);
    acc[nt] = __builtin_amdgcn_mfma_f32_16x16x32_f16(a1, b1, acc[nt], 0, 0, 0);
  }
  #pragma unroll
  for (int nt = 0; nt < 4; ++nt) {
    int c = nt * 16 + cr;
    float Ab = abbn[layer * 128 + c];
    float Bb = abbn[layer * 128 + 64 + c];
    #pragma unroll
    for (int r = 0; r < 4; ++r) {
      int row = wave * 16 + g * 4 + r;
      float v = fmaxf(fmaf(acc[nt][r], Ab, Bb), 0.f);
      tileH[row * DD + (((c >> 3) ^ (row & 7)) * 8) + (c & 7)] = __float2half(v);
    }
  }
  __syncthreads();
  const int arow = wave * 16 + cr;
  f16x8v a20 = *(const f16x8v*)(tileH + arow * DD + ((g ^ (arow & 7)) * 8));
  f16x8v a21 = *(const f16x8v*)(tileH + arow * DD + (((4 + g) ^ (arow & 7)) * 8));
  f32x4v acc2[4];
  #pragma unroll
  for (int nt = 0; nt < 4; ++nt) {
    f16x8v b0 = *(const f16x8v*)(w2l + (nt * 2 + 0) * 512 + lane * 8);
    f16x8v b1 = *(const f16x8v*)(w2l + (nt * 2 + 1) * 512 + lane * 8);
    acc2[nt] = (f32x4v){0.f, 0.f, 0.f, 0.f};
    acc2[nt] = __builtin_amdgcn_mfma_f32_16x16x32_f16(a20, b0, acc2[nt], 0, 0, 0);
    acc2[nt] = __builtin_amdgcn_mfma_f32_16x16x32_f16(a21, b1, acc2[nt], 0, 0, 0);
  }
  __syncthreads();
  #pragma unroll
  for (int nt = 0; nt < 4; ++nt) {
    int c = nt * 16 + cr;
    float bb = b2[layer * DD + c];
    #pragma unroll
    for (int r = 0; r < 4; ++r) {
      int row = wave * 16 + g * 4 + r;
      tileF[row * DD + ((c + row) & 63)] = fmaxf(acc2[nt][r] + bb, 0.f);
    }
  }
  __syncthreads();
  #pragma unroll
  for (int i = 0; i < 2; ++i) {
    int id = i * 256 + threadIdx.x;
    int rw = id >> 3, q = id & 7;
    if (n0 + rw < N) {
      f16x8v hv;
      #pragma unroll
      for (int j = 0; j < 8; ++j)
        hv[j] = (_Float16)tileF[rw * DD + ((q * 8 + j + rw) & 63)];
      *(f16x8v*)(hhout + (size_t)(n0 + rw) * DD + q * 8) = hv;
    }
  }
  float accp = 0.0f;
  int gcur = -1;
  for (int i = 0; i < 16; ++i) {
    int r = wave * 16 + i;
    int n = n0 + r;
    if (n >= N) break;
    float v = tileF[r * DD + ((lane + r) & 63)];
    int gb = batch[n];
    if (gb != gcur) {
      if (gcur >= 0) atomicAdd(&hcat[gcur * HC + layer * 128 + lane], accp);
      gcur = gb; accp = 0.0f;
    }
    accp = fmaf(v, pmask[n], accp);
  }
  if (gcur >= 0) atomicAdd(&hcat[gcur * HC + layer * 128 + lane], accp);
}

__global__ __launch_bounds__(256) void final_kernel(
    const float* __restrict__ hcat, const __half* __restrict__ h1,
    const __half* __restrict__ h2, const __half* __restrict__ h3,
    const int* __restrict__ mapping, const float* __restrict__ lw,
    const float* __restrict__ lb, float* __restrict__ out, int G)
{
  int gid = blockIdx.x * 256 + threadIdx.x;
  int g = gid >> 5, s = gid & 31;
  if (g >= G) return;
  float acc = lb[s];
  size_t mrow = (size_t)mapping[g] * DD;
  #pragma unroll
  for (int l = 0; l < 3; ++l) {
    const float* hc = hcat + g * HC + l * 128;
    const float* lwa = lw + (l * 128) * SS + s;
    #pragma unroll 4
    for (int c = 0; c < 64; ++c)
      acc = fmaf(hc[c], lwa[c * SS], acc);
    const __half* hr = ((l == 0) ? h1 : ((l == 1) ? h2 : h3)) + mrow;
    const float* lwc = lw + (l * 128 + 64) * SS + s;
    #pragma unroll 4
    for (int c = 0; c < 64; ++c)
      acc = fmaf(__half2float(hr[c]), lwc[c * SS], acc);
  }
  out[g * SS + s] = acc;
}

extern "C" void kernel_launch(void* const* d_in, const int* in_sizes, int n_in,
                              void* d_out, int out_size, void* d_ws, size_t ws_size,
                              hipStream_t stream)
{
  const float* x     = (const float*)d_in[0];
  const float* ew    = (const float*)d_in[1];
  const float* pmask = (const float*)d_in[2];
  const float* W1    = (const float*)d_in[3];
  const float* b1    = (const float*)d_in[4];
  const float* gma   = (const float*)d_in[5];
  const float* bta   = (const float*)d_in[6];
  const float* bnm   = (const float*)d_in[7];
  const float* bnv   = (const float*)d_in[8];
  const float* W2    = (const float*)d_in[9];
  const float* b2    = (const float*)d_in[10];
  const float* epsv  = (const float*)d_in[11];
  const float* lw    = (const float*)d_in[12];
  const float* lb    = (const float*)d_in[13];
  const int*   ei    = (const int*)d_in[14];
  const int*   batch = (const int*)d_in[15];
  const int*   mapping = (const int*)d_in[16];

  const int N = in_sizes[2];     // 50000 (< 65536 required for packing)
  const int E = in_sizes[1];
  const int G = in_sizes[16];
  const int nbins = (N + BINW - 1) / BINW;   // 196 <= 256
  const int nchunks = (E + CHUNK - 1) / CHUNK;
  const int prepb = (N * DD / 8 + 255) / 256;

  __half*   hh0  = (__half*)d_ws;                     // N*DD fp16 (x4 layers chained)
  __half*   hh1  = hh0 + (size_t)N * DD;
  __half*   hh2  = hh1 + (size_t)N * DD;
  __half*   hh3  = hh2 + (size_t)N * DD;
  __half*   zh   = hh3 + (size_t)N * DD;              // N*DD fp16 z scratch
  float*    hcat = (float*)(zh + (size_t)N * DD);     // G*HC      <-- memset 0
  int*      beg  = (int*)(hcat + (size_t)G * HC);     // N
  int*      endo = beg + N;                           // N
  int*      bin_cur = endo + N;                       // 256       <-- memset 0
  unsigned* packed  = (unsigned*)(bin_cur + 256);     // nbins*CAP
  unsigned* pk_slab = packed + (size_t)nbins * CAP;   // nbins*CAP
  unsigned short* dl_slab =
      (unsigned short*)(pk_slab + (size_t)nbins * CAP); // nbins*CAP
  __half*   wpk  = (__half*)(dl_slab + (size_t)nbins * CAP); // 24576 halves
  float*    abbn = (float*)(wpk + 24576);             // 384 floats
  float* fout = (float*)d_out;

  // ---- one memset covers hcat..bin_cur ----
  size_t zero_bytes = (size_t)G * HC * 4 + (size_t)N * 4 * 2 + 256 * 4;
  (void)hipMemsetAsync(hcat, 0, zero_bytes, stream);

  // ---- cooperative mega-kernel (grid clamped to co-resident capacity) ----
  int devId = 0;
  (void)hipGetDevice(&devId);
  int cus = 0;
  if (hipDeviceGetAttribute(&cus, hipDeviceAttributeMultiprocessorCount,
                            devId) != hipSuccess || cus <= 0)
    cus = 256;
  int maxb = 0;
  if (hipOccupancyMaxActiveBlocksPerMultiprocessor(
          &maxb, (const void*)mega_kernel, 256, 0) != hipSuccess || maxb < 1)
    maxb = 4;
  int bpc = maxb < 6 ? maxb : 6;
  int grid = bpc * cus;

  int Ei = E, Ni = N, Gi = G, nck = nchunks, nbi = nbins, ppb = prepb;
  void* kargs[] = {
    (void*)&ei, (void*)&ew, (void*)&bin_cur, (void*)&pk_slab, (void*)&dl_slab,
    (void*)&x, (void*)&hh0, (void*)&W1, (void*)&W2, (void*)&gma, (void*)&bta,
    (void*)&bnm, (void*)&bnv, (void*)&b1, (void*)&b2, (void*)&epsv,
    (void*)&pmask, (void*)&batch, (void*)&mapping, (void*)&lw, (void*)&lb,
    (void*)&wpk, (void*)&abbn, (void*)&zh, (void*)&hcat, (void*)&beg,
    (void*)&endo, (void*)&packed, (void*)&fout,
    (void*)&Ei, (void*)&Ni, (void*)&Gi, (void*)&nck, (void*)&nbi, (void*)&ppb };

  hipError_t st = hipLaunchCooperativeKernel(
      (const void*)mega_kernel, dim3(grid), dim3(256), kargs, 0, stream);

  if (st != hipSuccess) {
    // -------- fallback: classic split dispatches (R3 path) --------
    front_kernel<<<nchunks + prepb, 256, 0, stream>>>(
        ei, ew, bin_cur, pk_slab, dl_slab, E, nchunks,
        x, hh0, W1, W2, gma, bta, bnm, bnv, b1, wpk, abbn, N * DD);
    fine_csr_kernel<<<nbins, 256, 0, stream>>>(pk_slab, dl_slab, bin_cur,
                                               beg, endo, packed, N);
    __half* hhs[4] = {hh0, hh1, hh2, hh3};
    for (int layer = 0; layer < 3; ++layer) {
      gather_kernel<<<(N + 7) / 8, 256, 0, stream>>>(
          hhs[layer], packed, beg, endo, epsv, zh, layer, N);
      node_mfma_kernel<<<(N + 63) / 64, 256, 0, stream>>>(
          zh, hhs[layer + 1], wpk, abbn, b2, pmask, batch, hcat, layer, N);
    }
    final_kernel<<<(G * SS + 255) / 256, 256, 0, stream>>>(
        hcat, hh1, hh2, hh3, mapping, lw, lb, fout, G);
  }
}

// Round 6
// 288.776 us; speedup vs baseline: 6.9003x; 6.9003x over previous
//
#include <hip/hip_runtime.h>
#include <hip/hip_fp16.h>

#define DD 64
#define HC 384     // 2*D*L
#define SS 32
#define BINW 256   // nodes per bin (bin = dst >> 8); requires N < 65536
#define BSH 8
#define CAP 8192   // slab capacity per bin (avg load 4096 at E=800k)
#define CHUNK 2048 // edges per partition block

typedef _Float16 f16x8v __attribute__((ext_vector_type(8)));
typedef float f32x4v __attribute__((ext_vector_type(4)));

// ---------------- merged front-end: bin_part (blocks < nchunks) + prep ----------
// bin_cur is zero-initialized by hipMemsetAsync; slab offsets are relative.
// Wpk layout: idx = ((((layer*2+gemm)*4 + nt)*2 + kb)*64 + lane)*8 + j
//   value = W[layer][k = kb*32 + (lane>>4)*8 + j][c = nt*16 + (lane&15)]
// (A and B fragments use the same pi(g,j)=g*8+j k-permutation -> bijection, exact)
__global__ __launch_bounds__(256) void front_kernel(
    const int* __restrict__ ei, const float* __restrict__ ew,
    int* __restrict__ bin_cur, unsigned* __restrict__ pk_slab,
    unsigned short* __restrict__ dl_slab, int E, int nchunks,
    const float* __restrict__ x, __half* __restrict__ hh0,
    const float* __restrict__ W1, const float* __restrict__ W2,
    const float* __restrict__ gma, const float* __restrict__ bta,
    const float* __restrict__ bnm, const float* __restrict__ bnv,
    const float* __restrict__ b1, __half* __restrict__ wpk,
    float* __restrict__ abbn, int total)
{
  __shared__ unsigned spk[CHUNK];         // 8 KB
  __shared__ unsigned short sdst[CHUNK];  // 4 KB
  __shared__ int bcnt[256], boff[256], bcur[256], gbase[256], stmp[256];
  int t = threadIdx.x;

  if ((int)blockIdx.x >= nchunks) {
    // ---------------- prep part ----------------
    int gid = (blockIdx.x - nchunks) * 256 + t;
    if (gid < 3072) {                    // 3 layers * 2 gemms * 8 frag-blks * 64 lanes
      int lane_ = gid & 63;
      int rest = gid >> 6;               // (((ly*2+gm)*4+nt)*2+kb) in 0..47
      int kb = rest & 1;
      int nt = (rest >> 1) & 3;
      int gm = (rest >> 3) & 1;
      int ly = rest >> 4;
      const float* W = gm ? W2 : W1;
      int c = nt * 16 + (lane_ & 15);
      int k0 = kb * 32 + (lane_ >> 4) * 8;
      f16x8v o;
      #pragma unroll
      for (int j = 0; j < 8; ++j)
        o[j] = (_Float16)W[((size_t)ly * DD + k0 + j) * DD + c];
      *(f16x8v*)(wpk + gid * 8) = o;
    }
    if (gid >= 4096 && gid < 4288) {     // fold BN: A*t + B
      int id = gid - 4096;
      int ly = id >> 6, c = id & 63;
      float A = gma[ly * DD + c] * rsqrtf(bnv[ly * DD + c] + 1e-5f);
      float B = fmaf(b1[ly * DD + c] - bnm[ly * DD + c], A, bta[ly * DD + c]);
      abbn[ly * 128 + c] = A;
      abbn[ly * 128 + 64 + c] = B;
    }
    int i = gid * 8;
    if (i < total) {
      float4 a = *(const float4*)(x + i);
      float4 b = *(const float4*)(x + i + 4);
      __half2 o[4];
      o[0] = __floats2half2_rn(a.x, a.y);
      o[1] = __floats2half2_rn(a.z, a.w);
      o[2] = __floats2half2_rn(b.x, b.y);
      o[3] = __floats2half2_rn(b.z, b.w);
      *(float4*)(hh0 + i) = *(float4*)o;
    }
    return;
  }

  // ---------------- bin_part: partition edges into dst-bin slabs ----------------
  int e0 = blockIdx.x * CHUNK;
  int m = min(CHUNK, E - e0);
  bcnt[t] = 0;
  __syncthreads();
  for (int i = t; i < m; i += 256)
    atomicAdd(&bcnt[ei[E + e0 + i] >> BSH], 1);
  __syncthreads();
  int v = bcnt[t];
  stmp[t] = v;
  __syncthreads();
  for (int o = 1; o < 256; o <<= 1) {
    int u = (t >= o) ? stmp[t - o] : 0;
    __syncthreads();
    stmp[t] += u;
    __syncthreads();
  }
  boff[t] = stmp[t] - v;
  bcur[t] = stmp[t] - v;
  if (v > 0) gbase[t] = atomicAdd(&bin_cur[t], v);   // relative (zero-based)
  __syncthreads();
  for (int i = t; i < m; i += 256) {
    unsigned d = (unsigned)ei[E + e0 + i];
    int b = d >> BSH;
    int p = atomicAdd(&bcur[b], 1);
    unsigned short wh = __half_as_ushort(__float2half(ew[e0 + i]));
    spk[p] = (unsigned)ei[e0 + i] | ((unsigned)wh << 16);
    sdst[p] = (unsigned short)d;
  }
  __syncthreads();
  for (int i = t; i < m; i += 256) {
    unsigned short d = sdst[i];
    int b = d >> BSH;
    int g = b * CAP + gbase[b] + (i - boff[b]);
    pk_slab[g] = spk[i];
    dl_slab[g] = d;
  }
}

// one block per bin: local hist + scan -> rng[] (beg,end packed int2), scatter
// 4-byte records into the bin's own slab window of packed[] (L2-resident)
__global__ __launch_bounds__(256) void fine_csr_kernel(
    const unsigned* __restrict__ pk_slab,
    const unsigned short* __restrict__ dl_slab,
    const int* __restrict__ bin_cur, int2* __restrict__ rng,
    unsigned* __restrict__ packed, int N)
{
  __shared__ int cnt[256], loff[256], cur[256], stmp[256];
  int t = threadIdx.x;
  int b = blockIdx.x;
  int sbase = b * CAP;
  int m = bin_cur[b];                    // relative count
  cnt[t] = 0;
  __syncthreads();
  for (int i = t; i < m; i += 256)
    atomicAdd(&cnt[dl_slab[sbase + i] & 255], 1);
  __syncthreads();
  int v = cnt[t];
  stmp[t] = v;
  __syncthreads();
  for (int o = 1; o < 256; o <<= 1) {
    int u = (t >= o) ? stmp[t - o] : 0;
    __syncthreads();
    stmp[t] += u;
    __syncthreads();
  }
  loff[t] = stmp[t] - v;
  cur[t] = loff[t];
  int node = b * BINW + t;
  if (node < N) {
    int2 r;
    r.x = sbase + loff[t];
    r.y = sbase + loff[t] + v;
    rng[node] = r;
  }
  __syncthreads();
  for (int i = t; i < m; i += 256) {
    int dl = dl_slab[sbase + i] & 255;
    int p = atomicAdd(&cur[dl], 1);
    packed[sbase + p] = pk_slab[sbase + i];
  }
}

// ---------------- gather + z: FOUR nodes per wave; z written fp16 ----------------
// 8 edge-subgroups x 8 lanes; lane holds 8 channels (16 B fp16 row).
// Four independent edge-list chains per lane hide L2-miss latency (2x MLP of
// the previous 2-chain version; accumulation order per (node,sub,ch) unchanged
// -> bitwise-identical z).
__global__ __launch_bounds__(256) void gather_kernel(
    const __half* __restrict__ hh, const unsigned* __restrict__ packed,
    const int2* __restrict__ rng, const float* __restrict__ epsv,
    __half* __restrict__ zh, int layer, int N)
{
  int wave = threadIdx.x >> 6;
  int lane = threadIdx.x & 63;
  int sub = lane >> 3;          // 0..7
  int ch0 = (lane & 7) * 8;     // 8 channels per lane
  int n0 = blockIdx.x * 16 + wave * 4;
  if (n0 >= N) return;
  float acc[4][8];
  int e[4], en[4];
  #pragma unroll
  for (int c = 0; c < 4; ++c) {
    int n = n0 + c;
    int2 r;
    if (n < N) r = rng[n]; else { r.x = 0; r.y = 0; }
    e[c] = r.x + sub;
    en[c] = r.y;
    #pragma unroll
    for (int j = 0; j < 8; ++j) acc[c][j] = 0.f;
  }
  while (e[0] < en[0] || e[1] < en[1] || e[2] < en[2] || e[3] < en[3]) {
    unsigned pk[4];
    float4 r4[4];
    bool va[4];
    #pragma unroll
    for (int c = 0; c < 4; ++c) {
      va[c] = e[c] < en[c];
      if (va[c]) {
        pk[c] = packed[e[c]];
        r4[c] = *(const float4*)(hh + (size_t)(pk[c] & 0xffffu) * DD + ch0);
      }
    }
    #pragma unroll
    for (int c = 0; c < 4; ++c) {
      if (va[c]) {
        float w = __half2float(__ushort_as_half((unsigned short)(pk[c] >> 16)));
        const __half2* H = (const __half2*)&r4[c];
        #pragma unroll
        for (int j = 0; j < 4; ++j) {
          float2 f = __half22float2(H[j]);
          acc[c][2 * j]     = fmaf(w, f.x, acc[c][2 * j]);
          acc[c][2 * j + 1] = fmaf(w, f.y, acc[c][2 * j + 1]);
        }
      }
      e[c] += 8;
    }
  }
  #pragma unroll
  for (int c = 0; c < 4; ++c)
    #pragma unroll
    for (int j = 0; j < 8; ++j) {
      acc[c][j] += __shfl_xor(acc[c][j], 8);
      acc[c][j] += __shfl_xor(acc[c][j], 16);
      acc[c][j] += __shfl_xor(acc[c][j], 32);
    }
  if (sub == 0) {
    float e1 = 1.0f + epsv[layer];
    #pragma unroll
    for (int c = 0; c < 4; ++c) {
      int n = n0 + c;
      if (n < N) {
        float4 sr = *(const float4*)(hh + (size_t)n * DD + ch0);
        const __half2* S = (const __half2*)&sr;
        f16x8v q;
        #pragma unroll
        for (int j = 0; j < 4; ++j) {
          float2 f = __half22float2(S[j]);
          q[2 * j]     = (_Float16)fmaf(e1, f.x, acc[c][2 * j]);
          q[2 * j + 1] = (_Float16)fmaf(e1, f.y, acc[c][2 * j + 1]);
        }
        *(f16x8v*)(zh + (size_t)n * DD + ch0) = q;
      }
    }
  }
}

// ---------------- per-node GIN MLP via MFMA + pooling ----------------
// Block = 256 (4 waves) = 64 nodes. Wave w owns the 16-row m-tile w.
// GEMM1: A-frags straight from global fp16 z (row-major, 16B/lane),
//        B-frags from prepacked W (pi(g,j)=g*8+j on both sides -> exact).
// Transpose GEMM1->GEMM2 through fp16 LDS tile, XOR-swizzled 16B blocks
// (2-way bank reads = free). Final h kept fp32 in LDS for exact pooling.
// C/D layout: col=lane&15, row=(lane>>4)*4+reg (guide-verified, m89).
__global__ __launch_bounds__(256) void node_mfma_kernel(
    const __half* __restrict__ zh, __half* __restrict__ hhout,
    const __half* __restrict__ wpk, const float* __restrict__ abbn,
    const float* __restrict__ b2, const float* __restrict__ pmask,
    const int* __restrict__ batch, float* __restrict__ hcat,
    int layer, int N)
{
  __shared__ float tileF[DD * DD];       // 16 KB, reused across phases
  __half* tileH = (__half*)tileF;        // fp16 alias (first 8 KB)
  const int wave = threadIdx.x >> 6;
  const int lane = threadIdx.x & 63;
  const int g = lane >> 4;               // k-group
  const int cr = lane & 15;              // A-row / D-col within tile
  const int n0 = blockIdx.x * 64;
  const int mrow = n0 + wave * 16 + cr;  // node row for A fragments

  const __half* wl  = wpk + (size_t)layer * 8192;  // gemm1 pack
  const __half* w2l = wl + 4096;                   // gemm2 pack

  // ---- GEMM1: z @ W1 ----
  f16x8v a0 = *(const f16x8v*)(zh + (size_t)mrow * DD + g * 8);
  f16x8v a1 = *(const f16x8v*)(zh + (size_t)mrow * DD + 32 + g * 8);
  f32x4v acc[4];
  #pragma unroll
  for (int nt = 0; nt < 4; ++nt) {
    f16x8v b0 = *(const f16x8v*)(wl + (nt * 2 + 0) * 512 + lane * 8);
    f16x8v b1 = *(const f16x8v*)(wl + (nt * 2 + 1) * 512 + lane * 8);
    acc[nt] = (f32x4v){0.f, 0.f, 0.f, 0.f};
    acc[nt] = __builtin_amdgcn_mfma_f32_16x16x32_f16(a0, b0, acc[nt], 0, 0, 0);
    acc[nt] = __builtin_amdgcn_mfma_f32_16x16x32_f16(a1, b1, acc[nt], 0, 0, 0);
  }
  // ---- epilogue1: BN(fold A,B) + ReLU -> fp16 LDS (XOR-swizzled) ----
  #pragma unroll
  for (int nt = 0; nt < 4; ++nt) {
    int c = nt * 16 + cr;
    float Ab = abbn[layer * 128 + c];
    float Bb = abbn[layer * 128 + 64 + c];
    #pragma unroll
    for (int r = 0; r < 4; ++r) {
      int row = wave * 16 + g * 4 + r;
      float v = fmaxf(fmaf(acc[nt][r], Ab, Bb), 0.f);
      tileH[row * DD + (((c >> 3) ^ (row & 7)) * 8) + (c & 7)] = __float2half(v);
    }
  }
  __syncthreads();
  // ---- GEMM2: act @ W2 ----
  const int arow = wave * 16 + cr;
  f16x8v a20 = *(const f16x8v*)(tileH + arow * DD + ((g ^ (arow & 7)) * 8));
  f16x8v a21 = *(const f16x8v*)(tileH + arow * DD + (((4 + g) ^ (arow & 7)) * 8));
  f32x4v acc2[4];
  #pragma unroll
  for (int nt = 0; nt < 4; ++nt) {
    f16x8v b0 = *(const f16x8v*)(w2l + (nt * 2 + 0) * 512 + lane * 8);
    f16x8v b1 = *(const f16x8v*)(w2l + (nt * 2 + 1) * 512 + lane * 8);
    acc2[nt] = (f32x4v){0.f, 0.f, 0.f, 0.f};
    acc2[nt] = __builtin_amdgcn_mfma_f32_16x16x32_f16(a20, b0, acc2[nt], 0, 0, 0);
    acc2[nt] = __builtin_amdgcn_mfma_f32_16x16x32_f16(a21, b1, acc2[nt], 0, 0, 0);
  }
  __syncthreads();   // all A2 LDS reads done before tileF overwrite
  // ---- epilogue2: +b2, ReLU -> fp32 LDS (rotate-skewed) ----
  #pragma unroll
  for (int nt = 0; nt < 4; ++nt) {
    int c = nt * 16 + cr;
    float bb = b2[layer * DD + c];
    #pragma unroll
    for (int r = 0; r < 4; ++r) {
      int row = wave * 16 + g * 4 + r;
      tileF[row * DD + ((c + row) & 63)] = fmaxf(acc2[nt][r] + bb, 0.f);
    }
  }
  __syncthreads();
  // ---- copy-out h fp16, coalesced (8 threads per 128B row) ----
  #pragma unroll
  for (int i = 0; i < 2; ++i) {
    int id = i * 256 + threadIdx.x;
    int rw = id >> 3, q = id & 7;
    if (n0 + rw < N) {
      f16x8v hv;
      #pragma unroll
      for (int j = 0; j < 8; ++j)
        hv[j] = (_Float16)tileF[rw * DD + ((q * 8 + j + rw) & 63)];
      *(f16x8v*)(hhout + (size_t)(n0 + rw) * DD + q * 8) = hv;
    }
  }
  // ---- pooling (fp32-exact): wave w owns rows w*16..+15, lane = channel ----
  float accp = 0.0f;
  int gcur = -1;
  for (int i = 0; i < 16; ++i) {
    int r = wave * 16 + i;
    int n = n0 + r;
    if (n >= N) break;
    float v = tileF[r * DD + ((lane + r) & 63)];
    int gb = batch[n];                   // wave-uniform -> s_load
    if (gb != gcur) {
      if (gcur >= 0) atomicAdd(&hcat[gcur * HC + layer * 128 + lane], accp);
      gcur = gb; accp = 0.0f;
    }
    accp = fmaf(v, pmask[n], accp);
  }
  if (gcur >= 0) atomicAdd(&hcat[gcur * HC + layer * 128 + lane], accp);
}

// ---------------- final linear (+ fp16 center gather fused) ----------------
__global__ __launch_bounds__(256) void final_kernel(
    const float* __restrict__ hcat, const __half* __restrict__ h1,
    const __half* __restrict__ h2, const __half* __restrict__ h3,
    const int* __restrict__ mapping, const float* __restrict__ lw,
    const float* __restrict__ lb, float* __restrict__ out, int G)
{
  int gid = blockIdx.x * 256 + threadIdx.x;
  int g = gid >> 5, s = gid & 31;
  if (g >= G) return;
  float acc = lb[s];
  size_t mrow = (size_t)mapping[g] * DD;
  #pragma unroll
  for (int l = 0; l < 3; ++l) {
    const float* hc = hcat + g * HC + l * 128;
    const float* lwa = lw + (l * 128) * SS + s;
    #pragma unroll 4
    for (int c = 0; c < 64; ++c)
      acc = fmaf(hc[c], lwa[c * SS], acc);
    const __half* hr = ((l == 0) ? h1 : ((l == 1) ? h2 : h3)) + mrow;
    const float* lwc = lw + (l * 128 + 64) * SS + s;
    #pragma unroll 4
    for (int c = 0; c < 64; ++c)
      acc = fmaf(__half2float(hr[c]), lwc[c * SS], acc);
  }
  out[g * SS + s] = acc;
}

extern "C" void kernel_launch(void* const* d_in, const int* in_sizes, int n_in,
                              void* d_out, int out_size, void* d_ws, size_t ws_size,
                              hipStream_t stream)
{
  const float* x     = (const float*)d_in[0];
  const float* ew    = (const float*)d_in[1];
  const float* pmask = (const float*)d_in[2];
  const float* W1    = (const float*)d_in[3];
  const float* b1    = (const float*)d_in[4];
  const float* gma   = (const float*)d_in[5];
  const float* bta   = (const float*)d_in[6];
  const float* bnm   = (const float*)d_in[7];
  const float* bnv   = (const float*)d_in[8];
  const float* W2    = (const float*)d_in[9];
  const float* b2    = (const float*)d_in[10];
  const float* epsv  = (const float*)d_in[11];
  const float* lw    = (const float*)d_in[12];
  const float* lb    = (const float*)d_in[13];
  const int*   ei    = (const int*)d_in[14];
  const int*   batch = (const int*)d_in[15];
  const int*   mapping = (const int*)d_in[16];

  const int N = in_sizes[2];     // 50000 (< 65536 required for packing)
  const int E = in_sizes[1];
  const int G = in_sizes[16];
  const int nbins = (N + BINW - 1) / BINW;   // 196 <= 256
  const int nchunks = (E + CHUNK - 1) / CHUNK;
  const int prepb = (N * DD / 8 + 255) / 256;

  __half*   hh0  = (__half*)d_ws;                     // N*DD fp16
  __half*   hh1  = hh0 + (size_t)N * DD;              // N*DD
  __half*   hh2  = hh1 + (size_t)N * DD;              // N*DD
  __half*   hh3  = hh2 + (size_t)N * DD;              // N*DD
  __half*   zh   = hh3 + (size_t)N * DD;              // N*DD fp16 z scratch
  float*    hcat = (float*)(zh + (size_t)N * DD);     // G*HC      <-- memset 0
  int2*     rng  = (int2*)(hcat + (size_t)G * HC);    // N (beg,end)
  int*      bin_cur = (int*)(rng + N);                // 256       <-- memset 0
  unsigned* packed  = (unsigned*)(bin_cur + 256);     // nbins*CAP
  unsigned* pk_slab = packed + (size_t)nbins * CAP;   // nbins*CAP
  unsigned short* dl_slab =
      (unsigned short*)(pk_slab + (size_t)nbins * CAP); // nbins*CAP
  __half*   wpk  = (__half*)(dl_slab + (size_t)nbins * CAP); // 24576 halves
  float*    abbn = (float*)(wpk + 24576);             // 384 floats
  float* fout = (float*)d_out;

  // ---- one memset covers hcat..bin_cur (rng overwritten later anyway) ----
  size_t zero_bytes = (size_t)G * HC * 4 + (size_t)N * 8 + 256 * 4;
  (void)hipMemsetAsync(hcat, 0, zero_bytes, stream);

  // ---- merged front-end: edge binning + (x->fp16, W pack, BN fold) ----
  front_kernel<<<nchunks + prepb, 256, 0, stream>>>(
      ei, ew, bin_cur, pk_slab, dl_slab, E, nchunks,
      x, hh0, W1, W2, gma, bta, bnm, bnv, b1, wpk, abbn, N * DD);

  fine_csr_kernel<<<nbins, 256, 0, stream>>>(pk_slab, dl_slab, bin_cur,
                                             rng, packed, N);

  // ---- 3 GIN layers ----
  __half* hhs[4] = {hh0, hh1, hh2, hh3};
  for (int layer = 0; layer < 3; ++layer) {
    gather_kernel<<<(N + 15) / 16, 256, 0, stream>>>(
        hhs[layer], packed, rng, epsv, zh, layer, N);
    node_mfma_kernel<<<(N + 63) / 64, 256, 0, stream>>>(
        zh, hhs[layer + 1], wpk, abbn, b2, pmask, batch, hcat, layer, N);
  }
  final_kernel<<<(G * SS + 255) / 256, 256, 0, stream>>>(
      hcat, hh1, hh2, hh3, mapping, lw, lb, fout, G);
}

// Round 7
// 256.937 us; speedup vs baseline: 7.7554x; 1.1239x over previous
//
#include <hip/hip_runtime.h>
#include <hip/hip_fp16.h>

#define DD 64
#define HC 384     // 2*D*L
#define SS 32
#define BINW 256   // nodes per bin (bin = dst >> 8); requires N < 65536
#define BSH 8
#define CAP 8192   // slab capacity per bin (avg load 4096 at E=800k)
#define CHUNK 2048 // edges per partition block

typedef _Float16 f16x8v __attribute__((ext_vector_type(8)));
typedef float f32x4v __attribute__((ext_vector_type(4)));

// ---------------- merged front-end: bin_part (blocks < nchunks) + prep ----------
// bin_cur is zero-initialized by hipMemsetAsync; slab offsets are relative.
// Wpk layout: idx = ((((layer*2+gemm)*4 + nt)*2 + kb)*64 + lane)*8 + j
//   value = W[layer][k = kb*32 + (lane>>4)*8 + j][c = nt*16 + (lane&15)]
// (A and B fragments use the same pi(g,j)=g*8+j k-permutation -> bijection, exact)
__global__ __launch_bounds__(256) void front_kernel(
    const int* __restrict__ ei, const float* __restrict__ ew,
    int* __restrict__ bin_cur, unsigned* __restrict__ pk_slab,
    unsigned short* __restrict__ dl_slab, int E, int nchunks,
    const float* __restrict__ x, __half* __restrict__ hh0,
    const float* __restrict__ W1, const float* __restrict__ W2,
    const float* __restrict__ gma, const float* __restrict__ bta,
    const float* __restrict__ bnm, const float* __restrict__ bnv,
    const float* __restrict__ b1, __half* __restrict__ wpk,
    float* __restrict__ abbn, int total)
{
  __shared__ unsigned spk[CHUNK];         // 8 KB
  __shared__ unsigned short sdst[CHUNK];  // 4 KB
  __shared__ int bcnt[256], boff[256], bcur[256], gbase[256], stmp[256];
  int t = threadIdx.x;

  if ((int)blockIdx.x >= nchunks) {
    // ---------------- prep part ----------------
    int gid = (blockIdx.x - nchunks) * 256 + t;
    if (gid < 3072) {                    // 3 layers * 2 gemms * 8 frag-blks * 64 lanes
      int lane_ = gid & 63;
      int rest = gid >> 6;               // (((ly*2+gm)*4+nt)*2+kb) in 0..47
      int kb = rest & 1;
      int nt = (rest >> 1) & 3;
      int gm = (rest >> 3) & 1;
      int ly = rest >> 4;
      const float* W = gm ? W2 : W1;
      int c = nt * 16 + (lane_ & 15);
      int k0 = kb * 32 + (lane_ >> 4) * 8;
      f16x8v o;
      #pragma unroll
      for (int j = 0; j < 8; ++j)
        o[j] = (_Float16)W[((size_t)ly * DD + k0 + j) * DD + c];
      *(f16x8v*)(wpk + gid * 8) = o;
    }
    if (gid >= 4096 && gid < 4288) {     // fold BN: A*t + B
      int id = gid - 4096;
      int ly = id >> 6, c = id & 63;
      float A = gma[ly * DD + c] * rsqrtf(bnv[ly * DD + c] + 1e-5f);
      float B = fmaf(b1[ly * DD + c] - bnm[ly * DD + c], A, bta[ly * DD + c]);
      abbn[ly * 128 + c] = A;
      abbn[ly * 128 + 64 + c] = B;
    }
    int i = gid * 8;
    if (i < total) {
      float4 a = *(const float4*)(x + i);
      float4 b = *(const float4*)(x + i + 4);
      __half2 o[4];
      o[0] = __floats2half2_rn(a.x, a.y);
      o[1] = __floats2half2_rn(a.z, a.w);
      o[2] = __floats2half2_rn(b.x, b.y);
      o[3] = __floats2half2_rn(b.z, b.w);
      *(float4*)(hh0 + i) = *(float4*)o;
    }
    return;
  }

  // ---------------- bin_part: partition edges into dst-bin slabs ----------------
  int e0 = blockIdx.x * CHUNK;
  int m = min(CHUNK, E - e0);
  bcnt[t] = 0;
  __syncthreads();
  for (int i = t; i < m; i += 256)
    atomicAdd(&bcnt[ei[E + e0 + i] >> BSH], 1);
  __syncthreads();
  int v = bcnt[t];
  stmp[t] = v;
  __syncthreads();
  for (int o = 1; o < 256; o <<= 1) {
    int u = (t >= o) ? stmp[t - o] : 0;
    __syncthreads();
    stmp[t] += u;
    __syncthreads();
  }
  boff[t] = stmp[t] - v;
  bcur[t] = stmp[t] - v;
  if (v > 0) gbase[t] = atomicAdd(&bin_cur[t], v);   // relative (zero-based)
  __syncthreads();
  for (int i = t; i < m; i += 256) {
    unsigned d = (unsigned)ei[E + e0 + i];
    int b = d >> BSH;
    int p = atomicAdd(&bcur[b], 1);
    unsigned short wh = __half_as_ushort(__float2half(ew[e0 + i]));
    spk[p] = (unsigned)ei[e0 + i] | ((unsigned)wh << 16);
    sdst[p] = (unsigned short)d;
  }
  __syncthreads();
  for (int i = t; i < m; i += 256) {
    unsigned short d = sdst[i];
    int b = d >> BSH;
    int g = b * CAP + gbase[b] + (i - boff[b]);
    pk_slab[g] = spk[i];
    dl_slab[g] = d;
  }
}

// one block per bin: local hist + scan -> rng[] (beg,end packed int2), scatter
// 4-byte records into the bin's own slab window of packed[] (L2-resident)
__global__ __launch_bounds__(256) void fine_csr_kernel(
    const unsigned* __restrict__ pk_slab,
    const unsigned short* __restrict__ dl_slab,
    const int* __restrict__ bin_cur, int2* __restrict__ rng,
    unsigned* __restrict__ packed, int N)
{
  __shared__ int cnt[256], loff[256], cur[256], stmp[256];
  int t = threadIdx.x;
  int b = blockIdx.x;
  int sbase = b * CAP;
  int m = bin_cur[b];                    // relative count
  cnt[t] = 0;
  __syncthreads();
  for (int i = t; i < m; i += 256)
    atomicAdd(&cnt[dl_slab[sbase + i] & 255], 1);
  __syncthreads();
  int v = cnt[t];
  stmp[t] = v;
  __syncthreads();
  for (int o = 1; o < 256; o <<= 1) {
    int u = (t >= o) ? stmp[t - o] : 0;
    __syncthreads();
    stmp[t] += u;
    __syncthreads();
  }
  loff[t] = stmp[t] - v;
  cur[t] = loff[t];
  int node = b * BINW + t;
  if (node < N) {
    int2 r;
    r.x = sbase + loff[t];
    r.y = sbase + loff[t] + v;
    rng[node] = r;
  }
  __syncthreads();
  for (int i = t; i < m; i += 256) {
    int dl = dl_slab[sbase + i] & 255;
    int p = atomicAdd(&cur[dl], 1);
    packed[sbase + p] = pk_slab[sbase + i];
  }
}

// ---------------- gather + z: TWO nodes per wave; z written fp16 ----------------
// 8 edge-subgroups x 8 lanes; lane holds 8 channels (16 B fp16 row).
// Two independent edge-list chains per lane hide L2-miss latency; the NEXT
// iteration's packed[] word is prefetched one iteration ahead so the row load
// never waits on the index load (dependent-chain split).
__global__ __launch_bounds__(256) void gather_kernel(
    const __half* __restrict__ hh, const unsigned* __restrict__ packed,
    const int2* __restrict__ rng, const float* __restrict__ epsv,
    __half* __restrict__ zh, int layer, int N)
{
  int wave = threadIdx.x >> 6;
  int lane = threadIdx.x & 63;
  int sub = lane >> 3;          // 0..7
  int ch0 = (lane & 7) * 8;     // 8 channels per lane
  int na = blockIdx.x * 8 + wave * 2;
  int nb = na + 1;
  if (na >= N) return;
  bool hasB = nb < N;
  int2 rA = rng[na];
  int2 rB;
  if (hasB) rB = rng[nb]; else { rB.x = 0; rB.y = 0; }
  int ea = rA.x + sub, enda = rA.y;
  int eb = rB.x + sub, endb = rB.y;
  float accA[8] = {0, 0, 0, 0, 0, 0, 0, 0};
  float accB[8] = {0, 0, 0, 0, 0, 0, 0, 0};
  unsigned pa_n = (ea < enda) ? packed[ea] : 0;
  unsigned pb_n = (eb < endb) ? packed[eb] : 0;
  while (ea < enda || eb < endb) {
    bool va = ea < enda;
    bool vb = eb < endb;
    unsigned pa = pa_n, pb = pb_n;
    int ean = ea + 8, ebn = eb + 8;
    pa_n = (ean < enda) ? packed[ean] : 0;   // prefetch next index word
    pb_n = (ebn < endb) ? packed[ebn] : 0;
    float4 ra, rb;
    if (va) ra = *(const float4*)(hh + (size_t)(pa & 0xffffu) * DD + ch0);
    if (vb) rb = *(const float4*)(hh + (size_t)(pb & 0xffffu) * DD + ch0);
    if (va) {
      float w = __half2float(__ushort_as_half((unsigned short)(pa >> 16)));
      const __half2* H = (const __half2*)&ra;
      #pragma unroll
      for (int j = 0; j < 4; ++j) {
        float2 f = __half22float2(H[j]);
        accA[2 * j]     = fmaf(w, f.x, accA[2 * j]);
        accA[2 * j + 1] = fmaf(w, f.y, accA[2 * j + 1]);
      }
    }
    if (vb) {
      float w = __half2float(__ushort_as_half((unsigned short)(pb >> 16)));
      const __half2* H = (const __half2*)&rb;
      #pragma unroll
      for (int j = 0; j < 4; ++j) {
        float2 f = __half22float2(H[j]);
        accB[2 * j]     = fmaf(w, f.x, accB[2 * j]);
        accB[2 * j + 1] = fmaf(w, f.y, accB[2 * j + 1]);
      }
    }
    ea = ean; eb = ebn;
  }
  #pragma unroll
  for (int j = 0; j < 8; ++j) {
    accA[j] += __shfl_xor(accA[j], 8);
    accA[j] += __shfl_xor(accA[j], 16);
    accA[j] += __shfl_xor(accA[j], 32);
    accB[j] += __shfl_xor(accB[j], 8);
    accB[j] += __shfl_xor(accB[j], 16);
    accB[j] += __shfl_xor(accB[j], 32);
  }
  if (sub == 0) {
    float e1 = 1.0f + epsv[layer];
    {
      float4 sr = *(const float4*)(hh + (size_t)na * DD + ch0);
      const __half2* S = (const __half2*)&sr;
      f16x8v q;
      #pragma unroll
      for (int j = 0; j < 4; ++j) {
        float2 f = __half22float2(S[j]);
        q[2 * j]     = (_Float16)fmaf(e1, f.x, accA[2 * j]);
        q[2 * j + 1] = (_Float16)fmaf(e1, f.y, accA[2 * j + 1]);
      }
      *(f16x8v*)(zh + (size_t)na * DD + ch0) = q;
    }
    if (hasB) {
      float4 sr = *(const float4*)(hh + (size_t)nb * DD + ch0);
      const __half2* S = (const __half2*)&sr;
      f16x8v q;
      #pragma unroll
      for (int j = 0; j < 4; ++j) {
        float2 f = __half22float2(S[j]);
        q[2 * j]     = (_Float16)fmaf(e1, f.x, accB[2 * j]);
        q[2 * j + 1] = (_Float16)fmaf(e1, f.y, accB[2 * j + 1]);
      }
      *(f16x8v*)(zh + (size_t)nb * DD + ch0) = q;
    }
  }
}

// ---------------- per-node GIN MLP via MFMA + pooling ----------------
// Block = 256 (4 waves) = 64 nodes. Wave w owns the 16-row m-tile w.
// GEMM1: A-frags straight from global fp16 z (row-major, 16B/lane),
//        B-frags from prepacked W (pi(g,j)=g*8+j on both sides -> exact).
// Transpose GEMM1->GEMM2 through fp16 LDS tile, XOR-swizzled 16B blocks
// (2-way bank reads = free). Final h kept fp32 in LDS for exact pooling.
// C/D layout: col=lane&15, row=(lane>>4)*4+reg (guide-verified, m89).
__global__ __launch_bounds__(256) void node_mfma_kernel(
    const __half* __restrict__ zh, __half* __restrict__ hhout,
    const __half* __restrict__ wpk, const float* __restrict__ abbn,
    const float* __restrict__ b2, const float* __restrict__ pmask,
    const int* __restrict__ batch, float* __restrict__ hcat,
    int layer, int N)
{
  __shared__ float tileF[DD * DD];       // 16 KB, reused across phases
  __half* tileH = (__half*)tileF;        // fp16 alias (first 8 KB)
  const int wave = threadIdx.x >> 6;
  const int lane = threadIdx.x & 63;
  const int g = lane >> 4;               // k-group
  const int cr = lane & 15;              // A-row / D-col within tile
  const int n0 = blockIdx.x * 64;
  const int mrow = n0 + wave * 16 + cr;  // node row for A fragments

  const __half* wl  = wpk + (size_t)layer * 8192;  // gemm1 pack
  const __half* w2l = wl + 4096;                   // gemm2 pack

  // ---- GEMM1: z @ W1 ----
  f16x8v a0 = *(const f16x8v*)(zh + (size_t)mrow * DD + g * 8);
  f16x8v a1 = *(const f16x8v*)(zh + (size_t)mrow * DD + 32 + g * 8);
  f32x4v acc[4];
  #pragma unroll
  for (int nt = 0; nt < 4; ++nt) {
    f16x8v b0 = *(const f16x8v*)(wl + (nt * 2 + 0) * 512 + lane * 8);
    f16x8v b1 = *(const f16x8v*)(wl + (nt * 2 + 1) * 512 + lane * 8);
    acc[nt] = (f32x4v){0.f, 0.f, 0.f, 0.f};
    acc[nt] = __builtin_amdgcn_mfma_f32_16x16x32_f16(a0, b0, acc[nt], 0, 0, 0);
    acc[nt] = __builtin_amdgcn_mfma_f32_16x16x32_f16(a1, b1, acc[nt], 0, 0, 0);
  }
  // ---- epilogue1: BN(fold A,B) + ReLU -> fp16 LDS (XOR-swizzled) ----
  #pragma unroll
  for (int nt = 0; nt < 4; ++nt) {
    int c = nt * 16 + cr;
    float Ab = abbn[layer * 128 + c];
    float Bb = abbn[layer * 128 + 64 + c];
    #pragma unroll
    for (int r = 0; r < 4; ++r) {
      int row = wave * 16 + g * 4 + r;
      float v = fmaxf(fmaf(acc[nt][r], Ab, Bb), 0.f);
      tileH[row * DD + (((c >> 3) ^ (row & 7)) * 8) + (c & 7)] = __float2half(v);
    }
  }
  __syncthreads();
  // ---- GEMM2: act @ W2 ----
  const int arow = wave * 16 + cr;
  f16x8v a20 = *(const f16x8v*)(tileH + arow * DD + ((g ^ (arow & 7)) * 8));
  f16x8v a21 = *(const f16x8v*)(tileH + arow * DD + (((4 + g) ^ (arow & 7)) * 8));
  f32x4v acc2[4];
  #pragma unroll
  for (int nt = 0; nt < 4; ++nt) {
    f16x8v b0 = *(const f16x8v*)(w2l + (nt * 2 + 0) * 512 + lane * 8);
    f16x8v b1 = *(const f16x8v*)(w2l + (nt * 2 + 1) * 512 + lane * 8);
    acc2[nt] = (f32x4v){0.f, 0.f, 0.f, 0.f};
    acc2[nt] = __builtin_amdgcn_mfma_f32_16x16x32_f16(a20, b0, acc2[nt], 0, 0, 0);
    acc2[nt] = __builtin_amdgcn_mfma_f32_16x16x32_f16(a21, b1, acc2[nt], 0, 0, 0);
  }
  __syncthreads();   // all A2 LDS reads done before tileF overwrite
  // ---- epilogue2: +b2, ReLU -> fp32 LDS (rotate-skewed) ----
  #pragma unroll
  for (int nt = 0; nt < 4; ++nt) {
    int c = nt * 16 + cr;
    float bb = b2[layer * DD + c];
    #pragma unroll
    for (int r = 0; r < 4; ++r) {
      int row = wave * 16 + g * 4 + r;
      tileF[row * DD + ((c + row) & 63)] = fmaxf(acc2[nt][r] + bb, 0.f);
    }
  }
  __syncthreads();
  // ---- copy-out h fp16, coalesced (8 threads per 128B row) ----
  #pragma unroll
  for (int i = 0; i < 2; ++i) {
    int id = i * 256 + threadIdx.x;
    int rw = id >> 3, q = id & 7;
    if (n0 + rw < N) {
      f16x8v hv;
      #pragma unroll
      for (int j = 0; j < 8; ++j)
        hv[j] = (_Float16)tileF[rw * DD + ((q * 8 + j + rw) & 63)];
      *(f16x8v*)(hhout + (size_t)(n0 + rw) * DD + q * 8) = hv;
    }
  }
  // ---- pooling (fp32-exact): wave w owns rows w*16..+15, lane = channel ----
  float accp = 0.0f;
  int gcur = -1;
  for (int i = 0; i < 16; ++i) {
    int r = wave * 16 + i;
    int n = n0 + r;
    if (n >= N) break;
    float v = tileF[r * DD + ((lane + r) & 63)];
    int gb = batch[n];                   // wave-uniform -> s_load
    if (gb != gcur) {
      if (gcur >= 0) atomicAdd(&hcat[gcur * HC + layer * 128 + lane], accp);
      gcur = gb; accp = 0.0f;
    }
    accp = fmaf(v, pmask[n], accp);
  }
  if (gcur >= 0) atomicAdd(&hcat[gcur * HC + layer * 128 + lane], accp);
}

// ---------------- final linear (+ fp16 center gather fused) ----------------
__global__ __launch_bounds__(256) void final_kernel(
    const float* __restrict__ hcat, const __half* __restrict__ h1,
    const __half* __restrict__ h2, const __half* __restrict__ h3,
    const int* __restrict__ mapping, const float* __restrict__ lw,
    const float* __restrict__ lb, float* __restrict__ out, int G)
{
  int gid = blockIdx.x * 256 + threadIdx.x;
  int g = gid >> 5, s = gid & 31;
  if (g >= G) return;
  float acc = lb[s];
  size_t mrow = (size_t)mapping[g] * DD;
  #pragma unroll
  for (int l = 0; l < 3; ++l) {
    const float* hc = hcat + g * HC + l * 128;
    const float* lwa = lw + (l * 128) * SS + s;
    #pragma unroll 4
    for (int c = 0; c < 64; ++c)
      acc = fmaf(hc[c], lwa[c * SS], acc);
    const __half* hr = ((l == 0) ? h1 : ((l == 1) ? h2 : h3)) + mrow;
    const float* lwc = lw + (l * 128 + 64) * SS + s;
    #pragma unroll 4
    for (int c = 0; c < 64; ++c)
      acc = fmaf(__half2float(hr[c]), lwc[c * SS], acc);
  }
  out[g * SS + s] = acc;
}

extern "C" void kernel_launch(void* const* d_in, const int* in_sizes, int n_in,
                              void* d_out, int out_size, void* d_ws, size_t ws_size,
                              hipStream_t stream)
{
  const float* x     = (const float*)d_in[0];
  const float* ew    = (const float*)d_in[1];
  const float* pmask = (const float*)d_in[2];
  const float* W1    = (const float*)d_in[3];
  const float* b1    = (const float*)d_in[4];
  const float* gma   = (const float*)d_in[5];
  const float* bta   = (const float*)d_in[6];
  const float* bnm   = (const float*)d_in[7];
  const float* bnv   = (const float*)d_in[8];
  const float* W2    = (const float*)d_in[9];
  const float* b2    = (const float*)d_in[10];
  const float* epsv  = (const float*)d_in[11];
  const float* lw    = (const float*)d_in[12];
  const float* lb    = (const float*)d_in[13];
  const int*   ei    = (const int*)d_in[14];
  const int*   batch = (const int*)d_in[15];
  const int*   mapping = (const int*)d_in[16];

  const int N = in_sizes[2];     // 50000 (< 65536 required for packing)
  const int E = in_sizes[1];
  const int G = in_sizes[16];
  const int nbins = (N + BINW - 1) / BINW;   // 196 <= 256
  const int nchunks = (E + CHUNK - 1) / CHUNK;
  const int prepb = (N * DD / 8 + 255) / 256;

  __half*   hh0  = (__half*)d_ws;                     // N*DD fp16
  __half*   hh1  = hh0 + (size_t)N * DD;              // N*DD
  __half*   hh2  = hh1 + (size_t)N * DD;              // N*DD
  __half*   hh3  = hh2 + (size_t)N * DD;              // N*DD
  __half*   zh   = hh3 + (size_t)N * DD;              // N*DD fp16 z scratch
  float*    hcat = (float*)(zh + (size_t)N * DD);     // G*HC      <-- memset 0
  int2*     rng  = (int2*)(hcat + (size_t)G * HC);    // N (beg,end)
  int*      bin_cur = (int*)(rng + N);                // 256       <-- memset 0
  unsigned* packed  = (unsigned*)(bin_cur + 256);     // nbins*CAP
  unsigned* pk_slab = packed + (size_t)nbins * CAP;   // nbins*CAP
  unsigned short* dl_slab =
      (unsigned short*)(pk_slab + (size_t)nbins * CAP); // nbins*CAP
  __half*   wpk  = (__half*)(dl_slab + (size_t)nbins * CAP); // 24576 halves
  float*    abbn = (float*)(wpk + 24576);             // 384 floats
  float* fout = (float*)d_out;

  // ---- one memset covers hcat..bin_cur (rng overwritten later anyway) ----
  size_t zero_bytes = (size_t)G * HC * 4 + (size_t)N * 8 + 256 * 4;
  (void)hipMemsetAsync(hcat, 0, zero_bytes, stream);

  // ---- merged front-end: edge binning + (x->fp16, W pack, BN fold) ----
  front_kernel<<<nchunks + prepb, 256, 0, stream>>>(
      ei, ew, bin_cur, pk_slab, dl_slab, E, nchunks,
      x, hh0, W1, W2, gma, bta, bnm, bnv, b1, wpk, abbn, N * DD);

  fine_csr_kernel<<<nbins, 256, 0, stream>>>(pk_slab, dl_slab, bin_cur,
                                             rng, packed, N);

  // ---- 3 GIN layers ----
  __half* hhs[4] = {hh0, hh1, hh2, hh3};
  for (int layer = 0; layer < 3; ++layer) {
    gather_kernel<<<(N + 7) / 8, 256, 0, stream>>>(
        hhs[layer], packed, rng, epsv, zh, layer, N);
    node_mfma_kernel<<<(N + 63) / 64, 256, 0, stream>>>(
        zh, hhs[layer + 1], wpk, abbn, b2, pmask, batch, hcat, layer, N);
  }
  final_kernel<<<(G * SS + 255) / 256, 256, 0, stream>>>(
      hcat, hh1, hh2, hh3, mapping, lw, lb, fout, G);
}